// Round 9
// baseline (274.631 us; speedup 1.0000x reference)
//
#include <hip/hip_runtime.h>
#include <hip/hip_bf16.h>
#include <math.h>

#define D 64

typedef __attribute__((ext_vector_type(8))) short bf16x8;
typedef __attribute__((ext_vector_type(8))) _Float16 f16x8;
typedef __attribute__((ext_vector_type(8))) unsigned short u16x8;
typedef __attribute__((ext_vector_type(4))) float f32x4;
typedef unsigned short u16;

__device__ __forceinline__ float gelu_erf(float x) {
    return 0.5f * x * (1.0f + erff(x * 0.70710678118654752f));
}
// x * sigmoid(2u), u = 0.7978845608 x (1 + 0.044715 x^2); exp folded into exp2.
__device__ __forceinline__ float gelu_fast(float x) {
    float t = x * fmaf(x * x, -0.1029432f, -2.3022080f);   // -2u*log2(e)
    float e = __builtin_amdgcn_exp2f(t);                   // e^{-2u}
    return x * __builtin_amdgcn_rcpf(1.0f + e);            // x * sigmoid(2u)
}
__device__ __forceinline__ u16 f2bf(float v) {
    __hip_bfloat16 h = __float2bfloat16(v);
    return *(u16*)&h;
}
__device__ __forceinline__ float bf2f(u16 v) {
    return __uint_as_float(((unsigned int)v) << 16);
}
__device__ __forceinline__ u16 f2h(float v) {
    _Float16 h = (_Float16)v;
    return __builtin_bit_cast(u16, h);
}
__device__ __forceinline__ unsigned pk2h(float lo, float hi) {
    return (unsigned)f2h(lo) | ((unsigned)f2h(hi) << 16);
}
__device__ __forceinline__ void atomic_pk_add_u32(u16* addr, unsigned p) {
    asm volatile("global_atomic_pk_add_f16 %0, %1, off sc1" :: "v"(addr), "v"(p));
}
__device__ __forceinline__ void atomic_pk_add_f16(u16* addr, float lo, float hi) {
    atomic_pk_add_u32(addr, pk2h(lo, hi));
}
// pos p holds dim pi(p) = (p&3)*16 + (p>>2)
__device__ __forceinline__ int pi_perm(int p) { return ((p & 3) << 4) | (p >> 2); }

// 16-lane (DPP row) butterfly sum — all-VALU, no LDS latency.
__device__ __forceinline__ float rowsum16(float v) {
    int x;
    x = __builtin_amdgcn_update_dpp(0, __builtin_bit_cast(int, v), 0xB1, 0xF, 0xF, true);
    v += __builtin_bit_cast(float, x);
    x = __builtin_amdgcn_update_dpp(0, __builtin_bit_cast(int, v), 0x4E, 0xF, 0xF, true);
    v += __builtin_bit_cast(float, x);
    x = __builtin_amdgcn_update_dpp(0, __builtin_bit_cast(int, v), 0x141, 0xF, 0xF, true);
    v += __builtin_bit_cast(float, x);
    x = __builtin_amdgcn_update_dpp(0, __builtin_bit_cast(int, v), 0x140, 0xF, 0xF, true);
    v += __builtin_bit_cast(float, x);
    return v;
}

// ---- K1: weight B-fragment packing (blocks 0..11) + key histogram + per-edge rank
__global__ __launch_bounds__(256) void prep_hist(
    const float* __restrict__ Wt, const float* __restrict__ Wq,
    const float* __restrict__ Wks, const float* __restrict__ Wkd,
    const float* __restrict__ Wvs, const float* __restrict__ Wvd,
    u16* __restrict__ WtB, u16* __restrict__ WqB,
    u16* __restrict__ WksB, u16* __restrict__ WkdB,
    u16* __restrict__ WvsB, u16* __restrict__ WvdB,
    const int* __restrict__ ei, const float* __restrict__ esame,
    int* __restrict__ cnt, int* __restrict__ rank, int E)
{
    if (blockIdx.x < 12) {
        int task = blockIdx.x * 4 + (threadIdx.x >> 6);  // 0..47
        int lane = threadIdx.x & 63;
        int wsel = task >> 3, f = task & 7;
        int c = lane & 15, quad = lane >> 4;
        int nt = f >> 1, kk = f & 1;
        for (int j = 0; j < 8; ++j) {
            int n = nt * 16 + c, k = kk * 32 + quad * 8 + j;
            float v; u16* dp; bool h16 = false;
            switch (wsel) {
                case 0: v = Wt[n * 65 + k];  dp = WtB;  break;
                case 1: v = Wq[n * 64 + k];  dp = WqB;  break;
                case 2: v = Wks[k * 64 + n]; dp = WksB; break;
                case 3: v = Wkd[k * 64 + n]; dp = WkdB; break;
                case 4: v = Wvs[n * 64 + pi_perm(k)]; dp = WvsB; h16 = true; break;
                default: v = Wvd[n * 64 + pi_perm(k)]; dp = WvdB; h16 = true; break;
            }
            dp[(f * 64 + lane) * 8 + j] = h16 ? f2h(v) : f2bf(v);
        }
    } else {
        // 4 edges per thread, independent atomic chains (MLP)
        int gid = (blockIdx.x - 12) * 256 + threadIdx.x;
        int stride = (gridDim.x - 12) * 256;
        int e[4]; bool v[4]; int key[4];
        #pragma unroll
        for (int j = 0; j < 4; ++j) { e[j] = gid + j * stride; v[j] = e[j] < E; }
        #pragma unroll
        for (int j = 0; j < 4; ++j) {
            if (v[j]) key[j] = 2 * ei[E + e[j]] + (esame[e[j]] > 0.5f ? 0 : 1);
        }
        int r[4];
        #pragma unroll
        for (int j = 0; j < 4; ++j) {
            if (v[j]) r[j] = atomicAdd(&cnt[key[j]], 1);
        }
        #pragma unroll
        for (int j = 0; j < 4; ++j) {
            if (v[j]) rank[e[j]] = r[j];
        }
    }
}

// ---- K2: single-block exclusive scan (replaces scan_phaseA + scan_phaseC)
// 1024 threads, blocked ownership of ceil4(M/1024) elements each, int4 I/O.
#define SCAN_T 1024
__global__ __launch_bounds__(SCAN_T) void scan_one(const int* __restrict__ cnt,
                                                   int* __restrict__ cursor, int M)
{
    const int V = (((M + SCAN_T - 1) / SCAN_T) + 3) & ~3;   // 100 @ M=100k
    const int t = threadIdx.x;
    const int beg = t * V;

    // 1) per-thread sum of its block
    int s = 0;
    for (int j = 0; j < V; j += 4) {
        int idx = beg + j;
        if (idx + 3 < M) {
            int4 v = *(const int4*)(cnt + idx);
            s += v.x + v.y + v.z + v.w;
        } else {
            #pragma unroll
            for (int k = 0; k < 4; ++k) if (idx + k < M) s += cnt[idx + k];
        }
    }

    // 2) block-wide exclusive scan of the 1024 sums (wave scan + wave0 scan of wave-sums)
    const int lane = t & 63, w = t >> 6;   // 16 waves
    int inc = s;
    #pragma unroll
    for (int o = 1; o < 64; o <<= 1) {
        int v = __shfl_up(inc, o);
        if (lane >= o) inc += v;
    }
    __shared__ int wsum[16];
    __shared__ int woff[16];
    if (lane == 63) wsum[w] = inc;
    __syncthreads();
    if (w == 0) {
        int v = (lane < 16) ? wsum[lane] : 0;
        int a = v;
        #pragma unroll
        for (int o = 1; o < 16; o <<= 1) {
            int u = __shfl_up(a, o);
            if (lane >= o) a += u;
        }
        if (lane < 16) woff[lane] = a - v;   // exclusive wave offset
    }
    __syncthreads();
    int excl = woff[w] + (inc - s);

    // 3) rewalk: write exclusive prefix
    for (int j = 0; j < V; j += 4) {
        int idx = beg + j;
        bool full = (idx + 3 < M);
        int4 v = {0, 0, 0, 0};
        if (full) v = *(const int4*)(cnt + idx);
        else {
            #pragma unroll
            for (int k = 0; k < 4; ++k) ((int*)&v)[k] = (idx + k < M) ? cnt[idx + k] : 0;
        }
        int4 o;
        o.x = excl; excl += v.x;
        o.y = excl; excl += v.y;
        o.z = excl; excl += v.z;
        o.w = excl; excl += v.w;
        if (full) *(int4*)(cursor + idx) = o;
        else {
            #pragma unroll
            for (int k = 0; k < 4; ++k) if (idx + k < M) cursor[idx + k] = ((int*)&o)[k];
        }
    }
}

// ---- K3 (fat): blocks [0,GS) atomic-free counting-sort scatter (4 edges/thread) |
//                blocks [GS,GS+GQ) fused LN + q-chain; qgemm blocks also zero A+den
//                (zeroDst != nullptr) so the big memset node disappears.
__global__ __launch_bounds__(256) void scatter_qgemm(
    const int* __restrict__ ei, const float* __restrict__ et,
    const float* __restrict__ esame, const int* __restrict__ cursor,
    const int* __restrict__ rank,
    int4* __restrict__ evk, int E, int GS,
    const float* __restrict__ x, const float* __restrict__ gamma, const float* __restrict__ beta,
    const u16* __restrict__ WqB, const u16* __restrict__ WksB, const u16* __restrict__ WkdB,
    const float* __restrict__ bq, const float* __restrict__ bks, const float* __restrict__ bkd,
    u16* __restrict__ xnb, u16* __restrict__ qk2, float* __restrict__ bq2, int N,
    int4* __restrict__ zeroDst, long zeroN16)
{
    __shared__ u16 qtile[4][16 * 64];
    __shared__ u16 stile[4][32 * 64];

    if (blockIdx.x < GS) {
        int gid = blockIdx.x * 256 + threadIdx.x;
        int stride = GS * 256;
        int e[4]; bool v[4]; int key[4]; int rk[4]; int src[4]; float tv[4];
        #pragma unroll
        for (int j = 0; j < 4; ++j) { e[j] = gid + j * stride; v[j] = e[j] < E; }
        #pragma unroll
        for (int j = 0; j < 4; ++j) {
            if (v[j]) {
                key[j] = 2 * ei[E + e[j]] + (esame[e[j]] > 0.5f ? 0 : 1);
                rk[j] = rank[e[j]];
                src[j] = ei[e[j]];
                tv[j] = et[e[j]];
            }
        }
        int pos[4];
        #pragma unroll
        for (int j = 0; j < 4; ++j) {
            if (v[j]) pos[j] = cursor[key[j]] + rk[j];
        }
        #pragma unroll
        for (int j = 0; j < 4; ++j) {
            if (v[j]) evk[pos[j]] = make_int4(key[j], __float_as_int(tv[j]), src[j], 0);
        }
        return;
    }

    // ---------- qgemm ----------
    // cooperative zero of A+den (completes before edge_pass at kernel boundary)
    if (zeroDst) {
        const int nq = (int)gridDim.x - GS;
        for (long j = (long)(blockIdx.x - GS) * 256 + threadIdx.x; j < zeroN16;
             j += (long)nq * 256)
            zeroDst[j] = make_int4(0, 0, 0, 0);
    }

    const int lane = threadIdx.x & 63;
    const int c = lane & 15, quad = lane >> 4;
    const int w = threadIdx.x >> 6;
    const int wave = (blockIdx.x - GS) * 4 + w;
    const int n0r = wave * 16;
    const bool active = n0r < N;
    const int n0 = active ? n0r : 0;
    const int rowA = (n0 + c < N) ? n0 + c : N - 1;

    const float* xrow = x + (long)rowA * D;
    f32x4 xa = *(const f32x4*)(xrow + quad * 8);
    f32x4 xb = *(const f32x4*)(xrow + quad * 8 + 4);
    f32x4 xc = *(const f32x4*)(xrow + 32 + quad * 8);
    f32x4 xd = *(const f32x4*)(xrow + 32 + quad * 8 + 4);
    float s = 0.f, s2 = 0.f;
    #pragma unroll
    for (int j = 0; j < 4; ++j) {
        s += xa[j] + xb[j] + xc[j] + xd[j];
        s2 += xa[j] * xa[j] + xb[j] * xb[j] + xc[j] * xc[j] + xd[j] * xd[j];
    }
    s += __shfl_xor(s, 16);  s += __shfl_xor(s, 32);
    s2 += __shfl_xor(s2, 16); s2 += __shfl_xor(s2, 32);
    float mu = s * (1.0f / 64.0f);
    float var = s2 * (1.0f / 64.0f) - mu * mu;
    float rinv = rsqrtf(var + 1e-5f);
    f32x4 ga = *(const f32x4*)(gamma + quad * 8);
    f32x4 gb = *(const f32x4*)(gamma + quad * 8 + 4);
    f32x4 gc = *(const f32x4*)(gamma + 32 + quad * 8);
    f32x4 gd = *(const f32x4*)(gamma + 32 + quad * 8 + 4);
    f32x4 ba = *(const f32x4*)(beta + quad * 8);
    f32x4 bb = *(const f32x4*)(beta + quad * 8 + 4);
    f32x4 bc = *(const f32x4*)(beta + 32 + quad * 8);
    f32x4 bd = *(const f32x4*)(beta + 32 + quad * 8 + 4);
    bf16x8 a0, a1;
    #pragma unroll
    for (int j = 0; j < 4; ++j) {
        a0[j]     = (short)f2bf(fmaf((xa[j] - mu) * rinv, ga[j], ba[j]));
        a0[4 + j] = (short)f2bf(fmaf((xb[j] - mu) * rinv, gb[j], bb[j]));
        a1[j]     = (short)f2bf(fmaf((xc[j] - mu) * rinv, gc[j], bc[j]));
        a1[4 + j] = (short)f2bf(fmaf((xd[j] - mu) * rinv, gd[j], bd[j]));
    }
    *(bf16x8*)(xnb + (long)rowA * D + quad * 8) = a0;
    *(bf16x8*)(xnb + (long)rowA * D + 32 + quad * 8) = a1;

    float bqc[4], bksc[4], bkdc[4];
    #pragma unroll
    for (int t = 0; t < 4; ++t) {
        bqc[t] = bq[t * 16 + c]; bksc[t] = bks[t * 16 + c]; bkdc[t] = bkd[t * 16 + c];
    }

    // GEMM1: q
    f32x4 accq[4];
    #pragma unroll
    for (int t = 0; t < 4; ++t) {
        bf16x8 b0 = *(const bf16x8*)(WqB + ((t * 2 + 0) * 64 + lane) * 8);
        bf16x8 b1 = *(const bf16x8*)(WqB + ((t * 2 + 1) * 64 + lane) * 8);
        f32x4 z = {0.f, 0.f, 0.f, 0.f};
        z = __builtin_amdgcn_mfma_f32_16x16x32_bf16(a0, b0, z, 0, 0, 0);
        z = __builtin_amdgcn_mfma_f32_16x16x32_bf16(a1, b1, z, 0, 0, 0);
        accq[t] = z;
    }
    #pragma unroll
    for (int r = 0; r < 4; ++r) {
        float qv[4], ss = 0.f, sd = 0.f;
        #pragma unroll
        for (int t = 0; t < 4; ++t) {
            qv[t] = accq[t][r] + bqc[t];
            ss = fmaf(qv[t], bksc[t], ss);
            sd = fmaf(qv[t], bkdc[t], sd);
        }
        #pragma unroll
        for (int o = 1; o < 16; o <<= 1) { ss += __shfl_xor(ss, o); sd += __shfl_xor(sd, o); }
        int nrow = n0 + quad * 4 + r;
        if (active && c == 0 && nrow < N)
            *(float2*)(bq2 + 2 * nrow) = make_float2(ss, sd);
        #pragma unroll
        for (int t = 0; t < 4; ++t)
            qtile[w][(quad * 4 + r) * 64 + t * 16 + c] = f2bf(qv[t]);
    }
    __syncthreads();

    // GEMM2: qks/qkd -> stile rows (2m, 2m+1), pi-permuted positions
    const u16* qrow = &qtile[w][c * 64 + quad * 8];
    bf16x8 q0 = *(const bf16x8*)(qrow);
    bf16x8 q1 = *(const bf16x8*)(qrow + 32);
    #pragma unroll
    for (int t = 0; t < 4; ++t) {
        bf16x8 bs0 = *(const bf16x8*)(WksB + ((t * 2 + 0) * 64 + lane) * 8);
        bf16x8 bs1 = *(const bf16x8*)(WksB + ((t * 2 + 1) * 64 + lane) * 8);
        bf16x8 bd0 = *(const bf16x8*)(WkdB + ((t * 2 + 0) * 64 + lane) * 8);
        bf16x8 bd1 = *(const bf16x8*)(WkdB + ((t * 2 + 1) * 64 + lane) * 8);
        f32x4 zs = {0.f, 0.f, 0.f, 0.f}, zd = {0.f, 0.f, 0.f, 0.f};
        zs = __builtin_amdgcn_mfma_f32_16x16x32_bf16(q0, bs0, zs, 0, 0, 0);
        zs = __builtin_amdgcn_mfma_f32_16x16x32_bf16(q1, bs1, zs, 0, 0, 0);
        zd = __builtin_amdgcn_mfma_f32_16x16x32_bf16(q0, bd0, zd, 0, 0, 0);
        zd = __builtin_amdgcn_mfma_f32_16x16x32_bf16(q1, bd1, zd, 0, 0, 0);
        #pragma unroll
        for (int r = 0; r < 4; ++r) {
            int m = quad * 4 + r;
            stile[w][(2 * m + 0) * 64 + c * 4 + t] = f2bf(zs[r]);
            stile[w][(2 * m + 1) * 64 + c * 4 + t] = f2bf(zd[r]);
        }
    }
    __syncthreads();
    if (active) {
        int nrows = min(16, N - n0);
        const u16x8* sp = (const u16x8*)&stile[w][0];
        u16x8* dp = (u16x8*)(qk2 + (long)(2 * n0) * D);
        int cnt8 = nrows * 16;
        for (int j = lane; j < cnt8; j += 64) dp[j] = sp[j];
    }
}

// ---- K4: edge pass over key-sorted edges (run-aggregation in registers)
// R7-measured version: LDS wfrag, deferred stash flush, src prefetch, bias-in-C.
template<bool FULL>
__device__ __forceinline__ void edge_run(
    const int4* __restrict__ evk, const u16* __restrict__ xnb,
    const u16* wfrag, const float* btc, const float* w64c,
    const float* dvr, float phr,
    const u16* __restrict__ qk2, const float* __restrict__ bq2,
    u16* __restrict__ A, float* __restrict__ den,
    int base, int end, int qchunk, int c, int quad)
{
    const float S = 0.18033688011f;   // 0.125 * log2(e)
    const int lane = quad * 16 + c;
    int cur_key = -1;
    float racc0 = 0.f, racc1 = 0.f, racc2 = 0.f, racc3 = 0.f, rden = 0.f;
    ushort4 q4 = {0, 0, 0, 0};
    float bqv = 0.f;
    // deferred-flush stash (packed f16 pairs)
    int stash_key = -1; unsigned sp01 = 0, sp23 = 0; float srden = 0.f;

    const int rowbase = base + (c >> 2) * qchunk + (c & 3);
    const int qbase   = base + quad * qchunk;
    const int last    = end - 1;

    // prefetch src for i=0
    int srcC = ((const int*)(evk + (FULL ? rowbase : min(rowbase, last))))[2];

    for (int i = 0; i < qchunk; i += 4) {
        // xnb gather for current iteration (address already resident)
        const u16* ar = xnb + srcC * D + quad * 8;
        bf16x8 a0 = *(const bf16x8*)(ar);
        bf16x8 a1 = *(const bf16x8*)(ar + 32);

        // prefetch next iteration's src (clamped: stays in-bounds everywhere)
        srcC = ((const int*)(evk + min(rowbase + i + 4, last)))[2];

        int qb = qbase + i;
        int2 kt0 = *(const int2*)(evk + (FULL ? qb     : min(qb,     last)));
        int2 kt1 = *(const int2*)(evk + (FULL ? qb + 1 : min(qb + 1, last)));
        int2 kt2 = *(const int2*)(evk + (FULL ? qb + 2 : min(qb + 2, last)));
        int2 kt3 = *(const int2*)(evk + (FULL ? qb + 3 : min(qb + 3, last)));

        // flush stashed run AFTER this iteration's loads were issued:
        // atomics are younger than a0/a1/src/kt in the vmcnt FIFO.
        if (stash_key >= 0) {
            u16* ap = A + stash_key * D + c * 4;
            atomic_pk_add_u32(ap, sp01);
            atomic_pk_add_u32(ap + 2, sp23);
            if (c == 0) atomicAdd(&den[stash_key], srden);
            stash_key = -1;
        }

        // launder a zero LDS offset so the 8 fragment reads are not
        // loop-invariant (prevents LICM re-materializing them in VGPRs)
        unsigned woff = 0;
        asm volatile("" : "+v"(woff));
        const u16* wfx = wfrag + woff;

        f32x4 acc[4];
        #pragma unroll
        for (int t = 0; t < 4; ++t) {
            bf16x8 b0 = *(const bf16x8*)(wfx + ((t * 2 + 0) * 64 + lane) * 8);
            bf16x8 b1 = *(const bf16x8*)(wfx + ((t * 2 + 1) * 64 + lane) * 8);
            f32x4 z = {btc[t], btc[t], btc[t], btc[t]};   // bias-in-C
            z = __builtin_amdgcn_mfma_f32_16x16x32_bf16(a0, b0, z, 0, 0, 0);
            z = __builtin_amdgcn_mfma_f32_16x16x32_bf16(a1, b1, z, 0, 0, 0);
            acc[t] = z;
        }

        #pragma unroll
        for (int r = 0; r < 4; ++r) {
            int2 kt = (r == 0) ? kt0 : (r == 1) ? kt1 : (r == 2) ? kt2 : kt3;
            int keym = kt.x;
            float tm = __int_as_float(kt.y);

            float x0 = fmaf(tm, w64c[0], acc[0][r]);
            float x1 = fmaf(tm, w64c[1], acc[1][r]);
            float x2 = fmaf(tm, w64c[2], acc[2][r]);
            float x3 = fmaf(tm, w64c[3], acc[3][r]);
            float v0 = gelu_fast(x0) + __builtin_amdgcn_sinf(fmaf(tm, dvr[0], phr));
            float v1 = gelu_fast(x1) + __builtin_amdgcn_sinf(fmaf(tm, dvr[1], phr));
            float v2 = gelu_fast(x2) + __builtin_amdgcn_sinf(fmaf(tm, dvr[2], phr));
            float v3 = gelu_fast(x3) + __builtin_amdgcn_sinf(fmaf(tm, dvr[3], phr));

            if (keym != cur_key) {
                ushort4 nq = *(const ushort4*)(qk2 + keym * D + c * 4);
                float nb = bq2[keym];
                if (cur_key >= 0) {
                    if (stash_key >= 0) {   // rare: short run, stash occupied
                        u16* ap = A + stash_key * D + c * 4;
                        atomic_pk_add_u32(ap, sp01);
                        atomic_pk_add_u32(ap + 2, sp23);
                        if (c == 0) atomicAdd(&den[stash_key], srden);
                    }
                    sp01 = pk2h(racc0, racc1);
                    sp23 = pk2h(racc2, racc3);
                    srden = rden;
                    stash_key = cur_key;
                }
                cur_key = keym;
                q4 = nq;
                bqv = nb * S;
                racc0 = racc1 = racc2 = racc3 = 0.f;
                rden = 0.f;
            }

            float p = v0 * bf2f(q4.x);
            p = fmaf(v1, bf2f(q4.y), p);
            p = fmaf(v2, bf2f(q4.z), p);
            p = fmaf(v3, bf2f(q4.w), p);
            p = rowsum16(p);

            float ex = __builtin_amdgcn_exp2f(fmaf(p, S, bqv));
            if (!FULL && (qbase + i + r >= end)) ex = 0.f;

            racc0 = fmaf(ex, v0, racc0);
            racc1 = fmaf(ex, v1, racc1);
            racc2 = fmaf(ex, v2, racc2);
            racc3 = fmaf(ex, v3, racc3);
            rden += ex;   // ex is row-uniform; only lane c==0 flushes it
        }
    }

    if (stash_key >= 0) {
        u16* ap = A + stash_key * D + c * 4;
        atomic_pk_add_u32(ap, sp01);
        atomic_pk_add_u32(ap + 2, sp23);
        if (c == 0) atomicAdd(&den[stash_key], srden);
    }
    if (cur_key >= 0) {
        u16* ap = A + cur_key * D + c * 4;
        atomic_pk_add_f16(ap, racc0, racc1);
        atomic_pk_add_f16(ap + 2, racc2, racc3);
        if (c == 0) atomicAdd(&den[cur_key], rden);
    }
}

__global__ __launch_bounds__(256) void edge_pass(
    const int4* __restrict__ evk, const u16* __restrict__ xnb, const u16* __restrict__ WtB,
    const float* __restrict__ Wt, const float* __restrict__ bt,
    const u16* __restrict__ qk2, const float* __restrict__ bq2,
    u16* __restrict__ A, float* __restrict__ den, int E, int chunk)
{
    __shared__ u16 wfrag[4096];   // 8 KB: Wt B-fragments, shared by all 4 waves
    {
        u16x8* wf = (u16x8*)wfrag;
        const u16x8* ws = (const u16x8*)WtB;
        wf[threadIdx.x] = ws[threadIdx.x];
        wf[threadIdx.x + 256] = ws[threadIdx.x + 256];
    }
    __syncthreads();   // before any early exit (barrier with exited waves is UB)

    const int lane = threadIdx.x & 63;
    const int c = lane & 15, quad = lane >> 4;
    const int wave = blockIdx.x * 4 + (threadIdx.x >> 6);
    const int base = wave * chunk;
    if (base >= E) return;
    const int end = min(base + chunk, E);
    const int qchunk = chunk >> 2;

    float btc[4], w64c[4], dvr[4];
    #pragma unroll
    for (int t = 0; t < 4; ++t) {
        int dim = t * 16 + c;
        btc[t] = bt[dim];
        w64c[t] = Wt[dim * 65 + 64];
        // 200/(2*pi) * 10000^{-2*(dim/2)/64}  (v_sin consumes revolutions)
        dvr[t] = 31.830988618f * expf(-9.210340371976184f * (float)(2 * (dim >> 1)) * (1.0f / 64.0f));
    }
    const float phr = (c & 1) ? 0.25f : 0.0f;   // cos = sin(x + 1/4 rev)

    if (base + chunk <= E)
        edge_run<true>(evk, xnb, wfrag, btc, w64c, dvr, phr, qk2, bq2, A, den,
                       base, end, qchunk, c, quad);
    else
        edge_run<false>(evk, xnb, wfrag, btc, w64c, dvr, phr, qk2, bq2, A, den,
                        base, end, qchunk, c, quad);
}

// ---- K5: node post (MFMA value-GEMM + output)
__global__ __launch_bounds__(256) void vgemm(
    const float* __restrict__ x, const u16* __restrict__ A, const float* __restrict__ den,
    const u16* __restrict__ WvsB, const u16* __restrict__ WvdB,
    const float* __restrict__ bvs, const float* __restrict__ bvd,
    float* __restrict__ out, int N)
{
    const int lane = threadIdx.x & 63;
    const int c = lane & 15, quad = lane >> 4;
    const int wave = blockIdx.x * 4 + (threadIdx.x >> 6);
    const int n0 = wave * 16;
    if (n0 >= N) return;
    const int rowA = (n0 + c < N) ? n0 + c : N - 1;

    float bvsc[4], bvdc[4];
    #pragma unroll
    for (int t = 0; t < 4; ++t) { bvsc[t] = bvs[t * 16 + c]; bvdc[t] = bvd[t * 16 + c]; }

    const u16* srow = A + (long)(2 * rowA) * D + quad * 8;
    const u16* drow = A + (long)(2 * rowA + 1) * D + quad * 8;
    f16x8 s0 = *(const f16x8*)(srow);
    f16x8 s1 = *(const f16x8*)(srow + 32);
    f16x8 d0 = *(const f16x8*)(drow);
    f16x8 d1 = *(const f16x8*)(drow + 32);

    f32x4 oacc[4];
    #pragma unroll
    for (int t = 0; t < 4; ++t) {
        f16x8 bs0 = *(const f16x8*)(WvsB + ((t * 2 + 0) * 64 + lane) * 8);
        f16x8 bs1 = *(const f16x8*)(WvsB + ((t * 2 + 1) * 64 + lane) * 8);
        f16x8 bd0 = *(const f16x8*)(WvdB + ((t * 2 + 0) * 64 + lane) * 8);
        f16x8 bd1 = *(const f16x8*)(WvdB + ((t * 2 + 1) * 64 + lane) * 8);
        f32x4 z = {0.f, 0.f, 0.f, 0.f};
        z = __builtin_amdgcn_mfma_f32_16x16x32_f16(s0, bs0, z, 0, 0, 0);
        z = __builtin_amdgcn_mfma_f32_16x16x32_f16(s1, bs1, z, 0, 0, 0);
        z = __builtin_amdgcn_mfma_f32_16x16x32_f16(d0, bd0, z, 0, 0, 0);
        z = __builtin_amdgcn_mfma_f32_16x16x32_f16(d1, bd1, z, 0, 0, 0);
        oacc[t] = z;
    }

    #pragma unroll
    for (int r = 0; r < 4; ++r) {
        int n = n0 + quad * 4 + r;
        if (n >= N) continue;
        float ds = den[2 * n], dd = den[2 * n + 1];
        float inv = 1.0f / (ds + dd + 1e-16f);
        float fs = ds * inv, fd = dd * inv;
        #pragma unroll
        for (int t = 0; t < 4; ++t) {
            long idx = (long)n * D + t * 16 + c;
            float o = fmaf(oacc[t][r], inv, fmaf(fs, bvsc[t], fd * bvdc[t]));
            out[idx] = x[idx] + gelu_erf(o);
        }
    }
}

extern "C" void kernel_launch(void* const* d_in, const int* in_sizes, int n_in,
                              void* d_out, int out_size, void* d_ws, size_t ws_size,
                              hipStream_t stream) {
    const float* x        = (const float*)d_in[0];
    const int*   ei       = (const int*)d_in[1];
    const float* et       = (const float*)d_in[2];
    const float* esame    = (const float*)d_in[4];
    const float* ln_gamma = (const float*)d_in[5];
    const float* ln_beta  = (const float*)d_in[6];
    const float* Wt  = (const float*)d_in[7];
    const float* bt  = (const float*)d_in[8];
    const float* Wq  = (const float*)d_in[9];
    const float* bq  = (const float*)d_in[10];
    const float* Wks = (const float*)d_in[11];
    const float* bks = (const float*)d_in[12];
    const float* Wkd = (const float*)d_in[13];
    const float* bkd = (const float*)d_in[14];
    const float* Wvs = (const float*)d_in[15];
    const float* bvs = (const float*)d_in[16];
    const float* Wvd = (const float*)d_in[17];
    const float* bvd = (const float*)d_in[18];
    float* out = (float*)d_out;

    const int N = in_sizes[0] / D;   // 50000
    const int E = in_sizes[2];       // 800000
    const int M = 2 * N;             // key space

    u16* A      = (u16*)d_ws;
    float* den  = (float*)(A + (long)M * D);
    int* cnt    = (int*)(den + M);
    int* cursor = cnt + M;
    float* bq2  = (float*)(cursor + M);
    int4* evk   = (int4*)(bq2 + M);              // 16B-aligned
    int* bsum   = (int*)(evk + E);               // kept for layout stability (unused)
    u16* xnb    = (u16*)(bsum + 256);
    u16* qk2    = xnb + (long)N * D;
    u16* WtB    = qk2 + (long)M * D;
    u16* WqB    = WtB + 4096;
    u16* WksB   = WqB + 4096;
    u16* WkdB   = WksB + 4096;
    u16* WvsB   = WkdB + 4096;
    u16* WvdB   = WvsB + 4096;

    // rank: standalone after the weight buffers if workspace allows
    // (A+den then zeroed inside scatter_qgemm: no big memset node), else
    // overlay the front of A with the 2-memset fallback.
    char* wsend = (char*)(WvdB + 4096);
    const size_t usedBytes = (size_t)(wsend - (char*)d_ws);
    const size_t rankBytes = (size_t)E * 4;
    const bool rank_standalone = (ws_size >= usedBytes + rankBytes);
    int* rank = rank_standalone ? (int*)wsend : (int*)A;

    const size_t adBytes = (size_t)M * D * 2 + (size_t)M * 4;   // A + den (contiguous)

    if (rank_standalone) {
        hipMemsetAsync(cnt, 0, (size_t)M * 4, stream);          // cnt only (0.4 MB)
    } else {
        // zero cnt + everything of A past the rank overlay + den
        hipMemsetAsync((char*)A + rankBytes, 0,
                       (adBytes - rankBytes) + (size_t)M * 4, stream);
    }

    const int GH = (E + 256 * 4 - 1) / (256 * 4);     // histogram blocks, 4 edges/thread
    prep_hist<<<12 + GH, 256, 0, stream>>>(Wt, Wq, Wks, Wkd, Wvs, Wvd,
                                           WtB, WqB, WksB, WkdB, WvsB, WvdB,
                                           ei, esame, cnt, rank, E);

    scan_one<<<1, SCAN_T, 0, stream>>>(cnt, cursor, M);

    const int GS = (E + 256 * 4 - 1) / (256 * 4);     // scatter blocks (782), 4 edges/thread
    const int GQ = ((N + 15) / 16 + 3) / 4;           // qgemm blocks (782)
    scatter_qgemm<<<GS + GQ, 256, 0, stream>>>(
        ei, et, esame, cursor, rank, evk, E, GS,
        x, ln_gamma, ln_beta, WqB, WksB, WkdB, bq, bks, bkd,
        xnb, qk2, bq2, N,
        rank_standalone ? (int4*)A : (int4*)nullptr, (long)(adBytes / 16));

    if (!rank_standalone)
        hipMemsetAsync(A, 0, rankBytes, stream);   // rank prefix of A

    const int nwaves = 2048 * 4;
    const int chunk = ((E + nwaves * 16 - 1) / (nwaves * 16)) * 16;  // 112 @ E=800k
    edge_pass<<<2048, 256, 0, stream>>>(evk, xnb, WtB, Wt, bt,
                                        qk2, bq2, A, den, E, chunk);
    vgemm<<<GQ, 256, 0, stream>>>(x, A, den, WvsB, WvdB, bvs, bvd, out, N);
}

// Round 10
// 227.074 us; speedup vs baseline: 1.2094x; 1.2094x over previous
//
#include <hip/hip_runtime.h>
#include <hip/hip_bf16.h>
#include <math.h>

#define D 64

typedef __attribute__((ext_vector_type(8))) short bf16x8;
typedef __attribute__((ext_vector_type(8))) _Float16 f16x8;
typedef __attribute__((ext_vector_type(8))) unsigned short u16x8;
typedef __attribute__((ext_vector_type(4))) float f32x4;
typedef unsigned short u16;

__device__ __forceinline__ float gelu_erf(float x) {
    return 0.5f * x * (1.0f + erff(x * 0.70710678118654752f));
}
// x * sigmoid(2u), u = 0.7978845608 x (1 + 0.044715 x^2); exp folded into exp2.
__device__ __forceinline__ float gelu_fast(float x) {
    float t = x * fmaf(x * x, -0.1029432f, -2.3022080f);   // -2u*log2(e)
    float e = __builtin_amdgcn_exp2f(t);                   // e^{-2u}
    return x * __builtin_amdgcn_rcpf(1.0f + e);            // x * sigmoid(2u)
}
__device__ __forceinline__ u16 f2bf(float v) {
    __hip_bfloat16 h = __float2bfloat16(v);
    return *(u16*)&h;
}
__device__ __forceinline__ float bf2f(u16 v) {
    return __uint_as_float(((unsigned int)v) << 16);
}
__device__ __forceinline__ u16 f2h(float v) {
    _Float16 h = (_Float16)v;
    return __builtin_bit_cast(u16, h);
}
__device__ __forceinline__ unsigned pk2h(float lo, float hi) {
    return (unsigned)f2h(lo) | ((unsigned)f2h(hi) << 16);
}
__device__ __forceinline__ void atomic_pk_add_u32(u16* addr, unsigned p) {
    asm volatile("global_atomic_pk_add_f16 %0, %1, off sc1" :: "v"(addr), "v"(p));
}
__device__ __forceinline__ void atomic_pk_add_f16(u16* addr, float lo, float hi) {
    atomic_pk_add_u32(addr, pk2h(lo, hi));
}
// pos p holds dim pi(p) = (p&3)*16 + (p>>2)
__device__ __forceinline__ int pi_perm(int p) { return ((p & 3) << 4) | (p >> 2); }

// 16-lane (DPP row) butterfly sum — all-VALU, no LDS latency.
__device__ __forceinline__ float rowsum16(float v) {
    int x;
    x = __builtin_amdgcn_update_dpp(0, __builtin_bit_cast(int, v), 0xB1, 0xF, 0xF, true);
    v += __builtin_bit_cast(float, x);
    x = __builtin_amdgcn_update_dpp(0, __builtin_bit_cast(int, v), 0x4E, 0xF, 0xF, true);
    v += __builtin_bit_cast(float, x);
    x = __builtin_amdgcn_update_dpp(0, __builtin_bit_cast(int, v), 0x141, 0xF, 0xF, true);
    v += __builtin_bit_cast(float, x);
    x = __builtin_amdgcn_update_dpp(0, __builtin_bit_cast(int, v), 0x140, 0xF, 0xF, true);
    v += __builtin_bit_cast(float, x);
    return v;
}

// ---- K1: weight B-fragment packing (blocks 0..11) + key histogram + per-edge rank
__global__ __launch_bounds__(256) void prep_hist(
    const float* __restrict__ Wt, const float* __restrict__ Wq,
    const float* __restrict__ Wks, const float* __restrict__ Wkd,
    const float* __restrict__ Wvs, const float* __restrict__ Wvd,
    u16* __restrict__ WtB, u16* __restrict__ WqB,
    u16* __restrict__ WksB, u16* __restrict__ WkdB,
    u16* __restrict__ WvsB, u16* __restrict__ WvdB,
    const int* __restrict__ ei, const float* __restrict__ esame,
    int* __restrict__ cnt, int* __restrict__ rank, int E)
{
    if (blockIdx.x < 12) {
        int task = blockIdx.x * 4 + (threadIdx.x >> 6);  // 0..47
        int lane = threadIdx.x & 63;
        int wsel = task >> 3, f = task & 7;
        int c = lane & 15, quad = lane >> 4;
        int nt = f >> 1, kk = f & 1;
        for (int j = 0; j < 8; ++j) {
            int n = nt * 16 + c, k = kk * 32 + quad * 8 + j;
            float v; u16* dp; bool h16 = false;
            switch (wsel) {
                case 0: v = Wt[n * 65 + k];  dp = WtB;  break;
                case 1: v = Wq[n * 64 + k];  dp = WqB;  break;
                case 2: v = Wks[k * 64 + n]; dp = WksB; break;
                case 3: v = Wkd[k * 64 + n]; dp = WkdB; break;
                case 4: v = Wvs[n * 64 + pi_perm(k)]; dp = WvsB; h16 = true; break;
                default: v = Wvd[n * 64 + pi_perm(k)]; dp = WvdB; h16 = true; break;
            }
            dp[(f * 64 + lane) * 8 + j] = h16 ? f2h(v) : f2bf(v);
        }
    } else {
        // 4 edges per thread, independent atomic chains (MLP)
        int gid = (blockIdx.x - 12) * 256 + threadIdx.x;
        int stride = (gridDim.x - 12) * 256;
        int e[4]; bool v[4]; int key[4];
        #pragma unroll
        for (int j = 0; j < 4; ++j) { e[j] = gid + j * stride; v[j] = e[j] < E; }
        #pragma unroll
        for (int j = 0; j < 4; ++j) {
            if (v[j]) key[j] = 2 * ei[E + e[j]] + (esame[e[j]] > 0.5f ? 0 : 1);
        }
        int r[4];
        #pragma unroll
        for (int j = 0; j < 4; ++j) {
            if (v[j]) r[j] = atomicAdd(&cnt[key[j]], 1);
        }
        #pragma unroll
        for (int j = 0; j < 4; ++j) {
            if (v[j]) rank[e[j]] = r[j];
        }
    }
}

// ---- hierarchical scan: A) per-block reduce, C) local scan + self-computed offset
#define SCAN_CHUNK 2048

__global__ __launch_bounds__(256) void scan_phaseA(const int* __restrict__ cnt,
                                                   int* __restrict__ bsum, int M)
{
    int base = blockIdx.x * SCAN_CHUNK;
    int s = 0;
    for (int i = threadIdx.x; i < SCAN_CHUNK; i += 256) {
        int idx = base + i;
        s += (idx < M) ? cnt[idx] : 0;
    }
    #pragma unroll
    for (int o = 32; o; o >>= 1) s += __shfl_xor(s, o);
    __shared__ int red[4];
    if ((threadIdx.x & 63) == 0) red[threadIdx.x >> 6] = s;
    __syncthreads();
    if (threadIdx.x == 0) bsum[blockIdx.x] = red[0] + red[1] + red[2] + red[3];
}

__global__ __launch_bounds__(256) void scan_phaseC(const int* __restrict__ cnt,
                                                   const int* __restrict__ bsum,
                                                   int* __restrict__ cursor, int M)
{
    __shared__ int wsum[4];
    __shared__ int sboff;
    if (threadIdx.x < 64) {
        int v = ((int)threadIdx.x < (int)blockIdx.x) ? bsum[threadIdx.x] : 0;
        #pragma unroll
        for (int o = 32; o; o >>= 1) v += __shfl_xor(v, o);
        if (threadIdx.x == 0) sboff = v;
    }
    int base = blockIdx.x * SCAN_CHUNK;
    int i0 = base + threadIdx.x * 8;
    int vals[8];
    int tsum = 0;
    #pragma unroll
    for (int j = 0; j < 8; ++j) {
        int idx = i0 + j;
        vals[j] = (idx < M) ? cnt[idx] : 0;
        tsum += vals[j];
    }
    int lane = threadIdx.x & 63;
    int w = threadIdx.x >> 6;
    int inc = tsum;
    #pragma unroll
    for (int o = 1; o < 64; o <<= 1) {
        int v = __shfl_up(inc, o);
        if (lane >= o) inc += v;
    }
    if (lane == 63) wsum[w] = inc;
    __syncthreads();
    int woff = 0;
    #pragma unroll
    for (int k = 0; k < 4; ++k) woff += (k < w) ? wsum[k] : 0;
    int excl = woff + (inc - tsum) + sboff;
    #pragma unroll
    for (int j = 0; j < 8; ++j) {
        int idx = i0 + j;
        if (idx < M) cursor[idx] = excl;
        excl += vals[j];
    }
}

// ---- K3 (fat): blocks [0,GS) atomic-free counting-sort scatter (4 edges/thread) |
//                blocks [GS,GS+GQ) fused LN + q-chain; qgemm blocks also zero A+den
//                (zeroDst != nullptr) so the big memset node disappears.
__global__ __launch_bounds__(256) void scatter_qgemm(
    const int* __restrict__ ei, const float* __restrict__ et,
    const float* __restrict__ esame, const int* __restrict__ cursor,
    const int* __restrict__ rank,
    int4* __restrict__ evk, int E, int GS,
    const float* __restrict__ x, const float* __restrict__ gamma, const float* __restrict__ beta,
    const u16* __restrict__ WqB, const u16* __restrict__ WksB, const u16* __restrict__ WkdB,
    const float* __restrict__ bq, const float* __restrict__ bks, const float* __restrict__ bkd,
    u16* __restrict__ xnb, u16* __restrict__ qk2, float* __restrict__ bq2, int N,
    int4* __restrict__ zeroDst, long zeroN16)
{
    __shared__ u16 qtile[4][16 * 64];
    __shared__ u16 stile[4][32 * 64];

    if (blockIdx.x < GS) {
        int gid = blockIdx.x * 256 + threadIdx.x;
        int stride = GS * 256;
        int e[4]; bool v[4]; int key[4]; int rk[4]; int src[4]; float tv[4];
        #pragma unroll
        for (int j = 0; j < 4; ++j) { e[j] = gid + j * stride; v[j] = e[j] < E; }
        #pragma unroll
        for (int j = 0; j < 4; ++j) {
            if (v[j]) {
                key[j] = 2 * ei[E + e[j]] + (esame[e[j]] > 0.5f ? 0 : 1);
                rk[j] = rank[e[j]];
                src[j] = ei[e[j]];
                tv[j] = et[e[j]];
            }
        }
        int pos[4];
        #pragma unroll
        for (int j = 0; j < 4; ++j) {
            if (v[j]) pos[j] = cursor[key[j]] + rk[j];
        }
        #pragma unroll
        for (int j = 0; j < 4; ++j) {
            if (v[j]) evk[pos[j]] = make_int4(key[j], __float_as_int(tv[j]), src[j], 0);
        }
        return;
    }

    // ---------- qgemm ----------
    // cooperative zero of A+den (completes before edge_pass at kernel boundary)
    if (zeroDst) {
        const int nq = (int)gridDim.x - GS;
        for (long j = (long)(blockIdx.x - GS) * 256 + threadIdx.x; j < zeroN16;
             j += (long)nq * 256)
            zeroDst[j] = make_int4(0, 0, 0, 0);
    }

    const int lane = threadIdx.x & 63;
    const int c = lane & 15, quad = lane >> 4;
    const int w = threadIdx.x >> 6;
    const int wave = (blockIdx.x - GS) * 4 + w;
    const int n0r = wave * 16;
    const bool active = n0r < N;
    const int n0 = active ? n0r : 0;
    const int rowA = (n0 + c < N) ? n0 + c : N - 1;

    const float* xrow = x + (long)rowA * D;
    f32x4 xa = *(const f32x4*)(xrow + quad * 8);
    f32x4 xb = *(const f32x4*)(xrow + quad * 8 + 4);
    f32x4 xc = *(const f32x4*)(xrow + 32 + quad * 8);
    f32x4 xd = *(const f32x4*)(xrow + 32 + quad * 8 + 4);
    float s = 0.f, s2 = 0.f;
    #pragma unroll
    for (int j = 0; j < 4; ++j) {
        s += xa[j] + xb[j] + xc[j] + xd[j];
        s2 += xa[j] * xa[j] + xb[j] * xb[j] + xc[j] * xc[j] + xd[j] * xd[j];
    }
    s += __shfl_xor(s, 16);  s += __shfl_xor(s, 32);
    s2 += __shfl_xor(s2, 16); s2 += __shfl_xor(s2, 32);
    float mu = s * (1.0f / 64.0f);
    float var = s2 * (1.0f / 64.0f) - mu * mu;
    float rinv = rsqrtf(var + 1e-5f);
    f32x4 ga = *(const f32x4*)(gamma + quad * 8);
    f32x4 gb = *(const f32x4*)(gamma + quad * 8 + 4);
    f32x4 gc = *(const f32x4*)(gamma + 32 + quad * 8);
    f32x4 gd = *(const f32x4*)(gamma + 32 + quad * 8 + 4);
    f32x4 ba = *(const f32x4*)(beta + quad * 8);
    f32x4 bb = *(const f32x4*)(beta + quad * 8 + 4);
    f32x4 bc = *(const f32x4*)(beta + 32 + quad * 8);
    f32x4 bd = *(const f32x4*)(beta + 32 + quad * 8 + 4);
    bf16x8 a0, a1;
    #pragma unroll
    for (int j = 0; j < 4; ++j) {
        a0[j]     = (short)f2bf(fmaf((xa[j] - mu) * rinv, ga[j], ba[j]));
        a0[4 + j] = (short)f2bf(fmaf((xb[j] - mu) * rinv, gb[j], bb[j]));
        a1[j]     = (short)f2bf(fmaf((xc[j] - mu) * rinv, gc[j], bc[j]));
        a1[4 + j] = (short)f2bf(fmaf((xd[j] - mu) * rinv, gd[j], bd[j]));
    }
    *(bf16x8*)(xnb + (long)rowA * D + quad * 8) = a0;
    *(bf16x8*)(xnb + (long)rowA * D + 32 + quad * 8) = a1;

    float bqc[4], bksc[4], bkdc[4];
    #pragma unroll
    for (int t = 0; t < 4; ++t) {
        bqc[t] = bq[t * 16 + c]; bksc[t] = bks[t * 16 + c]; bkdc[t] = bkd[t * 16 + c];
    }

    // GEMM1: q
    f32x4 accq[4];
    #pragma unroll
    for (int t = 0; t < 4; ++t) {
        bf16x8 b0 = *(const bf16x8*)(WqB + ((t * 2 + 0) * 64 + lane) * 8);
        bf16x8 b1 = *(const bf16x8*)(WqB + ((t * 2 + 1) * 64 + lane) * 8);
        f32x4 z = {0.f, 0.f, 0.f, 0.f};
        z = __builtin_amdgcn_mfma_f32_16x16x32_bf16(a0, b0, z, 0, 0, 0);
        z = __builtin_amdgcn_mfma_f32_16x16x32_bf16(a1, b1, z, 0, 0, 0);
        accq[t] = z;
    }
    #pragma unroll
    for (int r = 0; r < 4; ++r) {
        float qv[4], ss = 0.f, sd = 0.f;
        #pragma unroll
        for (int t = 0; t < 4; ++t) {
            qv[t] = accq[t][r] + bqc[t];
            ss = fmaf(qv[t], bksc[t], ss);
            sd = fmaf(qv[t], bkdc[t], sd);
        }
        #pragma unroll
        for (int o = 1; o < 16; o <<= 1) { ss += __shfl_xor(ss, o); sd += __shfl_xor(sd, o); }
        int nrow = n0 + quad * 4 + r;
        if (active && c == 0 && nrow < N)
            *(float2*)(bq2 + 2 * nrow) = make_float2(ss, sd);
        #pragma unroll
        for (int t = 0; t < 4; ++t)
            qtile[w][(quad * 4 + r) * 64 + t * 16 + c] = f2bf(qv[t]);
    }
    __syncthreads();

    // GEMM2: qks/qkd -> stile rows (2m, 2m+1), pi-permuted positions
    const u16* qrow = &qtile[w][c * 64 + quad * 8];
    bf16x8 q0 = *(const bf16x8*)(qrow);
    bf16x8 q1 = *(const bf16x8*)(qrow + 32);
    #pragma unroll
    for (int t = 0; t < 4; ++t) {
        bf16x8 bs0 = *(const bf16x8*)(WksB + ((t * 2 + 0) * 64 + lane) * 8);
        bf16x8 bs1 = *(const bf16x8*)(WksB + ((t * 2 + 1) * 64 + lane) * 8);
        bf16x8 bd0 = *(const bf16x8*)(WkdB + ((t * 2 + 0) * 64 + lane) * 8);
        bf16x8 bd1 = *(const bf16x8*)(WkdB + ((t * 2 + 1) * 64 + lane) * 8);
        f32x4 zs = {0.f, 0.f, 0.f, 0.f}, zd = {0.f, 0.f, 0.f, 0.f};
        zs = __builtin_amdgcn_mfma_f32_16x16x32_bf16(q0, bs0, zs, 0, 0, 0);
        zs = __builtin_amdgcn_mfma_f32_16x16x32_bf16(q1, bs1, zs, 0, 0, 0);
        zd = __builtin_amdgcn_mfma_f32_16x16x32_bf16(q0, bd0, zd, 0, 0, 0);
        zd = __builtin_amdgcn_mfma_f32_16x16x32_bf16(q1, bd1, zd, 0, 0, 0);
        #pragma unroll
        for (int r = 0; r < 4; ++r) {
            int m = quad * 4 + r;
            stile[w][(2 * m + 0) * 64 + c * 4 + t] = f2bf(zs[r]);
            stile[w][(2 * m + 1) * 64 + c * 4 + t] = f2bf(zd[r]);
        }
    }
    __syncthreads();
    if (active) {
        int nrows = min(16, N - n0);
        const u16x8* sp = (const u16x8*)&stile[w][0];
        u16x8* dp = (u16x8*)(qk2 + (long)(2 * n0) * D);
        int cnt8 = nrows * 16;
        for (int j = lane; j < cnt8; j += 64) dp[j] = sp[j];
    }
}

// ---- K4: edge pass over key-sorted edges (run-aggregation in registers)
// R7-measured version: LDS wfrag, deferred stash flush, src prefetch, bias-in-C.
template<bool FULL>
__device__ __forceinline__ void edge_run(
    const int4* __restrict__ evk, const u16* __restrict__ xnb,
    const u16* wfrag, const float* btc, const float* w64c,
    const float* dvr, float phr,
    const u16* __restrict__ qk2, const float* __restrict__ bq2,
    u16* __restrict__ A, float* __restrict__ den,
    int base, int end, int qchunk, int c, int quad)
{
    const float S = 0.18033688011f;   // 0.125 * log2(e)
    const int lane = quad * 16 + c;
    int cur_key = -1;
    float racc0 = 0.f, racc1 = 0.f, racc2 = 0.f, racc3 = 0.f, rden = 0.f;
    ushort4 q4 = {0, 0, 0, 0};
    float bqv = 0.f;
    // deferred-flush stash (packed f16 pairs)
    int stash_key = -1; unsigned sp01 = 0, sp23 = 0; float srden = 0.f;

    const int rowbase = base + (c >> 2) * qchunk + (c & 3);
    const int qbase   = base + quad * qchunk;
    const int last    = end - 1;

    // prefetch src for i=0
    int srcC = ((const int*)(evk + (FULL ? rowbase : min(rowbase, last))))[2];

    for (int i = 0; i < qchunk; i += 4) {
        // xnb gather for current iteration (address already resident)
        const u16* ar = xnb + srcC * D + quad * 8;
        bf16x8 a0 = *(const bf16x8*)(ar);
        bf16x8 a1 = *(const bf16x8*)(ar + 32);

        // prefetch next iteration's src (clamped: stays in-bounds everywhere)
        srcC = ((const int*)(evk + min(rowbase + i + 4, last)))[2];

        int qb = qbase + i;
        int2 kt0 = *(const int2*)(evk + (FULL ? qb     : min(qb,     last)));
        int2 kt1 = *(const int2*)(evk + (FULL ? qb + 1 : min(qb + 1, last)));
        int2 kt2 = *(const int2*)(evk + (FULL ? qb + 2 : min(qb + 2, last)));
        int2 kt3 = *(const int2*)(evk + (FULL ? qb + 3 : min(qb + 3, last)));

        // flush stashed run AFTER this iteration's loads were issued:
        // atomics are younger than a0/a1/src/kt in the vmcnt FIFO.
        if (stash_key >= 0) {
            u16* ap = A + stash_key * D + c * 4;
            atomic_pk_add_u32(ap, sp01);
            atomic_pk_add_u32(ap + 2, sp23);
            if (c == 0) atomicAdd(&den[stash_key], srden);
            stash_key = -1;
        }

        // launder a zero LDS offset so the 8 fragment reads are not
        // loop-invariant (prevents LICM re-materializing them in VGPRs)
        unsigned woff = 0;
        asm volatile("" : "+v"(woff));
        const u16* wfx = wfrag + woff;

        f32x4 acc[4];
        #pragma unroll
        for (int t = 0; t < 4; ++t) {
            bf16x8 b0 = *(const bf16x8*)(wfx + ((t * 2 + 0) * 64 + lane) * 8);
            bf16x8 b1 = *(const bf16x8*)(wfx + ((t * 2 + 1) * 64 + lane) * 8);
            f32x4 z = {btc[t], btc[t], btc[t], btc[t]};   // bias-in-C
            z = __builtin_amdgcn_mfma_f32_16x16x32_bf16(a0, b0, z, 0, 0, 0);
            z = __builtin_amdgcn_mfma_f32_16x16x32_bf16(a1, b1, z, 0, 0, 0);
            acc[t] = z;
        }

        #pragma unroll
        for (int r = 0; r < 4; ++r) {
            int2 kt = (r == 0) ? kt0 : (r == 1) ? kt1 : (r == 2) ? kt2 : kt3;
            int keym = kt.x;
            float tm = __int_as_float(kt.y);

            float x0 = fmaf(tm, w64c[0], acc[0][r]);
            float x1 = fmaf(tm, w64c[1], acc[1][r]);
            float x2 = fmaf(tm, w64c[2], acc[2][r]);
            float x3 = fmaf(tm, w64c[3], acc[3][r]);
            float v0 = gelu_fast(x0) + __builtin_amdgcn_sinf(fmaf(tm, dvr[0], phr));
            float v1 = gelu_fast(x1) + __builtin_amdgcn_sinf(fmaf(tm, dvr[1], phr));
            float v2 = gelu_fast(x2) + __builtin_amdgcn_sinf(fmaf(tm, dvr[2], phr));
            float v3 = gelu_fast(x3) + __builtin_amdgcn_sinf(fmaf(tm, dvr[3], phr));

            if (keym != cur_key) {
                ushort4 nq = *(const ushort4*)(qk2 + keym * D + c * 4);
                float nb = bq2[keym];
                if (cur_key >= 0) {
                    if (stash_key >= 0) {   // rare: short run, stash occupied
                        u16* ap = A + stash_key * D + c * 4;
                        atomic_pk_add_u32(ap, sp01);
                        atomic_pk_add_u32(ap + 2, sp23);
                        if (c == 0) atomicAdd(&den[stash_key], srden);
                    }
                    sp01 = pk2h(racc0, racc1);
                    sp23 = pk2h(racc2, racc3);
                    srden = rden;
                    stash_key = cur_key;
                }
                cur_key = keym;
                q4 = nq;
                bqv = nb * S;
                racc0 = racc1 = racc2 = racc3 = 0.f;
                rden = 0.f;
            }

            float p = v0 * bf2f(q4.x);
            p = fmaf(v1, bf2f(q4.y), p);
            p = fmaf(v2, bf2f(q4.z), p);
            p = fmaf(v3, bf2f(q4.w), p);
            p = rowsum16(p);

            float ex = __builtin_amdgcn_exp2f(fmaf(p, S, bqv));
            if (!FULL && (qbase + i + r >= end)) ex = 0.f;

            racc0 = fmaf(ex, v0, racc0);
            racc1 = fmaf(ex, v1, racc1);
            racc2 = fmaf(ex, v2, racc2);
            racc3 = fmaf(ex, v3, racc3);
            rden += ex;   // ex is row-uniform; only lane c==0 flushes it
        }
    }

    if (stash_key >= 0) {
        u16* ap = A + stash_key * D + c * 4;
        atomic_pk_add_u32(ap, sp01);
        atomic_pk_add_u32(ap + 2, sp23);
        if (c == 0) atomicAdd(&den[stash_key], srden);
    }
    if (cur_key >= 0) {
        u16* ap = A + cur_key * D + c * 4;
        atomic_pk_add_f16(ap, racc0, racc1);
        atomic_pk_add_f16(ap + 2, racc2, racc3);
        if (c == 0) atomicAdd(&den[cur_key], rden);
    }
}

__global__ __launch_bounds__(256) void edge_pass(
    const int4* __restrict__ evk, const u16* __restrict__ xnb, const u16* __restrict__ WtB,
    const float* __restrict__ Wt, const float* __restrict__ bt,
    const u16* __restrict__ qk2, const float* __restrict__ bq2,
    u16* __restrict__ A, float* __restrict__ den, int E, int chunk)
{
    __shared__ u16 wfrag[4096];   // 8 KB: Wt B-fragments, shared by all 4 waves
    {
        u16x8* wf = (u16x8*)wfrag;
        const u16x8* ws = (const u16x8*)WtB;
        wf[threadIdx.x] = ws[threadIdx.x];
        wf[threadIdx.x + 256] = ws[threadIdx.x + 256];
    }
    __syncthreads();   // before any early exit (barrier with exited waves is UB)

    const int lane = threadIdx.x & 63;
    const int c = lane & 15, quad = lane >> 4;
    const int wave = blockIdx.x * 4 + (threadIdx.x >> 6);
    const int base = wave * chunk;
    if (base >= E) return;
    const int end = min(base + chunk, E);
    const int qchunk = chunk >> 2;

    float btc[4], w64c[4], dvr[4];
    #pragma unroll
    for (int t = 0; t < 4; ++t) {
        int dim = t * 16 + c;
        btc[t] = bt[dim];
        w64c[t] = Wt[dim * 65 + 64];
        // 200/(2*pi) * 10000^{-2*(dim/2)/64}  (v_sin consumes revolutions)
        dvr[t] = 31.830988618f * expf(-9.210340371976184f * (float)(2 * (dim >> 1)) * (1.0f / 64.0f));
    }
    const float phr = (c & 1) ? 0.25f : 0.0f;   // cos = sin(x + 1/4 rev)

    if (base + chunk <= E)
        edge_run<true>(evk, xnb, wfrag, btc, w64c, dvr, phr, qk2, bq2, A, den,
                       base, end, qchunk, c, quad);
    else
        edge_run<false>(evk, xnb, wfrag, btc, w64c, dvr, phr, qk2, bq2, A, den,
                        base, end, qchunk, c, quad);
}

// ---- K5: node post (MFMA value-GEMM + output)
__global__ __launch_bounds__(256) void vgemm(
    const float* __restrict__ x, const u16* __restrict__ A, const float* __restrict__ den,
    const u16* __restrict__ WvsB, const u16* __restrict__ WvdB,
    const float* __restrict__ bvs, const float* __restrict__ bvd,
    float* __restrict__ out, int N)
{
    const int lane = threadIdx.x & 63;
    const int c = lane & 15, quad = lane >> 4;
    const int wave = blockIdx.x * 4 + (threadIdx.x >> 6);
    const int n0 = wave * 16;
    if (n0 >= N) return;
    const int rowA = (n0 + c < N) ? n0 + c : N - 1;

    float bvsc[4], bvdc[4];
    #pragma unroll
    for (int t = 0; t < 4; ++t) { bvsc[t] = bvs[t * 16 + c]; bvdc[t] = bvd[t * 16 + c]; }

    const u16* srow = A + (long)(2 * rowA) * D + quad * 8;
    const u16* drow = A + (long)(2 * rowA + 1) * D + quad * 8;
    f16x8 s0 = *(const f16x8*)(srow);
    f16x8 s1 = *(const f16x8*)(srow + 32);
    f16x8 d0 = *(const f16x8*)(drow);
    f16x8 d1 = *(const f16x8*)(drow + 32);

    f32x4 oacc[4];
    #pragma unroll
    for (int t = 0; t < 4; ++t) {
        f16x8 bs0 = *(const f16x8*)(WvsB + ((t * 2 + 0) * 64 + lane) * 8);
        f16x8 bs1 = *(const f16x8*)(WvsB + ((t * 2 + 1) * 64 + lane) * 8);
        f16x8 bd0 = *(const f16x8*)(WvdB + ((t * 2 + 0) * 64 + lane) * 8);
        f16x8 bd1 = *(const f16x8*)(WvdB + ((t * 2 + 1) * 64 + lane) * 8);
        f32x4 z = {0.f, 0.f, 0.f, 0.f};
        z = __builtin_amdgcn_mfma_f32_16x16x32_f16(s0, bs0, z, 0, 0, 0);
        z = __builtin_amdgcn_mfma_f32_16x16x32_f16(s1, bs1, z, 0, 0, 0);
        z = __builtin_amdgcn_mfma_f32_16x16x32_f16(d0, bd0, z, 0, 0, 0);
        z = __builtin_amdgcn_mfma_f32_16x16x32_f16(d1, bd1, z, 0, 0, 0);
        oacc[t] = z;
    }

    #pragma unroll
    for (int r = 0; r < 4; ++r) {
        int n = n0 + quad * 4 + r;
        if (n >= N) continue;
        float ds = den[2 * n], dd = den[2 * n + 1];
        float inv = 1.0f / (ds + dd + 1e-16f);
        float fs = ds * inv, fd = dd * inv;
        #pragma unroll
        for (int t = 0; t < 4; ++t) {
            long idx = (long)n * D + t * 16 + c;
            float o = fmaf(oacc[t][r], inv, fmaf(fs, bvsc[t], fd * bvdc[t]));
            out[idx] = x[idx] + gelu_erf(o);
        }
    }
}

extern "C" void kernel_launch(void* const* d_in, const int* in_sizes, int n_in,
                              void* d_out, int out_size, void* d_ws, size_t ws_size,
                              hipStream_t stream) {
    const float* x        = (const float*)d_in[0];
    const int*   ei       = (const int*)d_in[1];
    const float* et       = (const float*)d_in[2];
    const float* esame    = (const float*)d_in[4];
    const float* ln_gamma = (const float*)d_in[5];
    const float* ln_beta  = (const float*)d_in[6];
    const float* Wt  = (const float*)d_in[7];
    const float* bt  = (const float*)d_in[8];
    const float* Wq  = (const float*)d_in[9];
    const float* bq  = (const float*)d_in[10];
    const float* Wks = (const float*)d_in[11];
    const float* bks = (const float*)d_in[12];
    const float* Wkd = (const float*)d_in[13];
    const float* bkd = (const float*)d_in[14];
    const float* Wvs = (const float*)d_in[15];
    const float* bvs = (const float*)d_in[16];
    const float* Wvd = (const float*)d_in[17];
    const float* bvd = (const float*)d_in[18];
    float* out = (float*)d_out;

    const int N = in_sizes[0] / D;   // 50000
    const int E = in_sizes[2];       // 800000
    const int M = 2 * N;             // key space

    u16* A      = (u16*)d_ws;
    float* den  = (float*)(A + (long)M * D);
    int* cnt    = (int*)(den + M);
    int* cursor = cnt + M;
    float* bq2  = (float*)(cursor + M);
    int4* evk   = (int4*)(bq2 + M);              // 16B-aligned
    int* bsum   = (int*)(evk + E);               // scan block sums (<=256)
    u16* xnb    = (u16*)(bsum + 256);
    u16* qk2    = xnb + (long)N * D;
    u16* WtB    = qk2 + (long)M * D;
    u16* WqB    = WtB + 4096;
    u16* WksB   = WqB + 4096;
    u16* WkdB   = WksB + 4096;
    u16* WvsB   = WkdB + 4096;
    u16* WvdB   = WvsB + 4096;

    // rank: standalone after the weight buffers if workspace allows
    // (A+den then zeroed inside scatter_qgemm: no big memset node), else
    // overlay the front of A with the 2-memset fallback.
    char* wsend = (char*)(WvdB + 4096);
    const size_t usedBytes = (size_t)(wsend - (char*)d_ws);
    const size_t rankBytes = (size_t)E * 4;
    const bool rank_standalone = (ws_size >= usedBytes + rankBytes);
    int* rank = rank_standalone ? (int*)wsend : (int*)A;

    const size_t adBytes = (size_t)M * D * 2 + (size_t)M * 4;   // A + den (contiguous)

    if (rank_standalone) {
        hipMemsetAsync(cnt, 0, (size_t)M * 4, stream);          // cnt only (0.4 MB)
    } else {
        // zero cnt + everything of A past the rank overlay + den
        hipMemsetAsync((char*)A + rankBytes, 0,
                       (adBytes - rankBytes) + (size_t)M * 4, stream);
    }

    const int GH = (E + 256 * 4 - 1) / (256 * 4);     // histogram blocks, 4 edges/thread
    prep_hist<<<12 + GH, 256, 0, stream>>>(Wt, Wq, Wks, Wkd, Wvs, Wvd,
                                           WtB, WqB, WksB, WkdB, WvsB, WvdB,
                                           ei, esame, cnt, rank, E);

    const int nbScan = (M + SCAN_CHUNK - 1) / SCAN_CHUNK;   // 49 @ M=100k (must stay <= 64)
    scan_phaseA<<<nbScan, 256, 0, stream>>>(cnt, bsum, M);
    scan_phaseC<<<nbScan, 256, 0, stream>>>(cnt, bsum, cursor, M);

    const int GS = (E + 256 * 4 - 1) / (256 * 4);     // scatter blocks (782), 4 edges/thread
    const int GQ = ((N + 15) / 16 + 3) / 4;           // qgemm blocks (782)
    scatter_qgemm<<<GS + GQ, 256, 0, stream>>>(
        ei, et, esame, cursor, rank, evk, E, GS,
        x, ln_gamma, ln_beta, WqB, WksB, WkdB, bq, bks, bkd,
        xnb, qk2, bq2, N,
        rank_standalone ? (int4*)A : (int4*)nullptr, (long)(adBytes / 16));

    if (!rank_standalone)
        hipMemsetAsync(A, 0, rankBytes, stream);   // rank prefix of A

    const int nwaves = 2048 * 4;
    const int chunk = ((E + nwaves * 16 - 1) / (nwaves * 16)) * 16;  // 112 @ E=800k
    edge_pass<<<2048, 256, 0, stream>>>(evk, xnb, WtB, Wt, bt,
                                        qk2, bq2, A, den, E, chunk);
    vgemm<<<GQ, 256, 0, stream>>>(x, A, den, WvsB, WvdB, bvs, bvd, out, N);
}